// Round 14
// baseline (354.898 us; speedup 1.0000x reference)
//
#include <hip/hip_runtime.h>

#define GG 64        // graphs
#define STRIDE 10240 // per-bin region capacity (mean 8704 -> big headroom)
#define NBINMAX 256  // bins = dst>>9, N<=131072

typedef __attribute__((ext_vector_type(8))) short short8;   // 8 bf16 (4 VGPR)
typedef __attribute__((ext_vector_type(4))) float f32x4;    // 4 fp32 acc

// ---------------- bf16 helpers ----------------

__device__ inline unsigned short bf16rne(float f) {
  unsigned int x = __float_as_uint(f);
  unsigned int r = (x + 0x7FFFu + ((x >> 16) & 1u)) >> 16;
  return (unsigned short)r;
}
__device__ inline unsigned int pack2(float a, float b) {
  return (unsigned int)bf16rne(a) | ((unsigned int)bf16rne(b) << 16);
}
__device__ inline float blo(unsigned int v) { return __uint_as_float(v << 16); }
__device__ inline float bhi(unsigned int v) { return __uint_as_float(v & 0xFFFF0000u); }

// ---------------- edge partition, level 1: coarse bins ----------------

__global__ __launch_bounds__(256) void part_p1(const int* __restrict__ ei,
                                               int* __restrict__ gcur,
                                               unsigned int* __restrict__ pairs,
                                               int E, int N) {
  __shared__ int hist[NBINMAX];
  __shared__ int gbase[NBINMAX];
  __shared__ int lcur[NBINMAX];
  int t = threadIdx.x;
  int tot = E + N;
  int base = blockIdx.x * 4096;
  hist[t] = 0;
  __syncthreads();
  int sarr[16], darr[16];
  #pragma unroll
  for (int k = 0; k < 16; ++k) {
    int i = base + k * 256 + t;
    if (i < tot) {
      int s, d;
      if (i < E) { s = ei[i]; d = ei[E + i]; } else { s = i - E; d = s; }
      sarr[k] = s; darr[k] = d;
      atomicAdd(&hist[d >> 9], 1);
    } else darr[k] = -1;
  }
  __syncthreads();
  int c = hist[t];
  gbase[t] = (c > 0) ? atomicAdd(&gcur[t], c) : 0;
  lcur[t] = 0;
  __syncthreads();
  #pragma unroll
  for (int k = 0; k < 16; ++k) {
    int d = darr[k];
    if (d >= 0) {
      int b = d >> 9;
      int p = gbase[b] + atomicAdd(&lcur[b], 1);
      pairs[p] = ((unsigned int)(d & 511) << 17) | (unsigned int)sarr[k];
    }
  }
}

// ---------------- edge partition, level 2: exact CSR within bin ----------------

__global__ __launch_bounds__(256) void part_p2(const unsigned int* __restrict__ pairs,
                                               const int* __restrict__ gcur,
                                               int* __restrict__ ssrc,
                                               int* __restrict__ offsets,
                                               int* __restrict__ counts, int N) {
  __shared__ int ncnt[512], ncur[512], excl_s[512];
  __shared__ int wsum[4];
  int b = blockIdx.x;
  int t = threadIdx.x;
  int pb = b * STRIDE;
  int cnt = gcur[b] - pb;
  ncnt[t] = 0; ncnt[t + 256] = 0;
  __syncthreads();
  for (int e = t; e < cnt; e += 256) {
    unsigned int v = pairs[pb + e];
    atomicAdd(&ncnt[v >> 17], 1);
  }
  __syncthreads();
  int c0 = ncnt[2 * t], c1 = ncnt[2 * t + 1];
  int ps = c0 + c1;
  int lane = t & 63, w = t >> 6;
  int x = ps;
  #pragma unroll
  for (int s = 1; s < 64; s <<= 1) { int y = __shfl_up(x, s); if (lane >= s) x += y; }
  if (lane == 63) wsum[w] = x;
  __syncthreads();
  int woff = 0;
  for (int i = 0; i < w; ++i) woff += wsum[i];
  int ep = woff + x - ps;
  excl_s[2 * t]     = ep;
  excl_s[2 * t + 1] = ep + c0;
  __syncthreads();
  int binstart = b << 9;
  for (int i = t; i < 512; i += 256) {
    ncur[i] = excl_s[i];
    int node = binstart + i;
    if (node < N) { offsets[node] = pb + excl_s[i]; counts[node] = ncnt[i]; }
  }
  __syncthreads();
  for (int e = t; e < cnt; e += 256) {
    unsigned int v = pairs[pb + e];
    int dl = v >> 17;
    int p = atomicAdd(&ncur[dl], 1);
    ssrc[pb + p] = (int)(v & 0x1FFFF);
  }
}

// ---------------- graph boundaries (batch is sorted) ----------------

__global__ __launch_bounds__(256) void gbounds(const int* __restrict__ batch,
                                               int* __restrict__ gstart, int N) {
  int i = blockIdx.x * 256 + threadIdx.x;
  if (i >= N) return;
  int g = batch[i];
  if (i == 0 || batch[i - 1] != g) gstart[g] = i;
}

// wave-parallel: inclusive suffix-min of valid starts, then shift by 1
__global__ __launch_bounds__(64) void gfix(const int* __restrict__ gstart,
                                           int* __restrict__ go,
                                           int* __restrict__ ge, int N) {
  int g = threadIdx.x;                 // 64 lanes = 64 graphs
  int s = gstart[g];
  int v = (s < 0) ? 0x7FFFFFFF : s;
  int suf = v;
  #pragma unroll
  for (int off = 1; off < 64; off <<= 1) {
    int x = __shfl_down(suf, off);
    if (g + off < 64) suf = min(suf, x);
  }
  int nxt = __shfl_down(suf, 1);       // suffix-min over lanes > g
  if (g == 63) nxt = 0x7FFFFFFF;
  int e = nxt == 0x7FFFFFFF ? N : nxt;
  if (s < 0) { go[g] = e; ge[g] = e; }
  else       { go[g] = s; ge[g] = e; }
}

// ---------------- prep: weight transpose/split + gcur init ----------------

__global__ __launch_bounds__(256) void wprep(const float* __restrict__ w0,
                                             const float* __restrict__ w1,
                                             unsigned short* __restrict__ wt,
                                             int* __restrict__ gcur) {
  if (blockIdx.x == 0) gcur[threadIdx.x] = threadIdx.x * STRIDE;
  int idx = blockIdx.x * 256 + threadIdx.x;   // 0..32767
  int layer = idx >> 14;
  int e = idx & 16383;
  int k = e >> 7, n = e & 127;
  float v = (layer ? w1 : w0)[e];
  unsigned short hi = bf16rne(v);
  float hif = __uint_as_float((unsigned int)hi << 16);
  unsigned short lo = bf16rne(v - hif);
  unsigned short* basep = wt + layer * 32768;
  basep[n * 128 + k] = hi;
  basep[16384 + n * 128 + k] = lo;
}

// ---------------- MFMA bf16-split GEMM [N,128]@[128,128] + attn logits ----
// Barrier-free / LDS-free: each lane loads its A-fragment directly from
// global (per rt the wave covers 16 rows x 128B contiguous -> full lines),
// truncation-splits hi/lo in registers, feeds MFMA. 16 independent (rt,kt)
// chains per wave -> deep ILP, no __syncthreads anywhere.
// Wave w: head w&1, row-half w>>1; col-half = blockIdx&1.

__global__ __launch_bounds__(256) void gemm_mfma(
    const float* __restrict__ in, const unsigned short* __restrict__ wtL,
    const float* __restrict__ att_s, const float* __restrict__ att_d,
    unsigned int* __restrict__ h16, float* __restrict__ a_s,
    float* __restrict__ a_d, int N) {
  int t = threadIdx.x;
  int bid = blockIdx.x;
  int ch = bid & 1;               // column half (heads 2ch, 2ch+1)
  int base = (bid >> 1) * 128;    // row base
  int lane = t & 63, w = t >> 6;
  int l15 = lane & 15, lg = lane >> 4;
  int hd = w & 1;                 // head within this col-half
  int n0 = ch * 64 + hd * 32;     // global col base for this wave
  int rh = w >> 1;                // row half

  f32x4 zero4 = {0.f, 0.f, 0.f, 0.f};
  f32x4 acc[4][2];
  #pragma unroll
  for (int rt = 0; rt < 4; ++rt) { acc[rt][0] = zero4; acc[rt][1] = zero4; }

  // per-rt A row pointers (col chunk lg*8, 32B per lane per kt)
  const float* ap[4];
  #pragma unroll
  for (int rt = 0; rt < 4; ++rt) {
    int row = base + rh * 64 + rt * 16 + l15;
    int rc = row < N ? row : (N - 1);
    ap[rt] = &in[(size_t)rc * 128 + lg * 8];
  }
  // B-frag row pointers (ushort elements; +16384 = lo plane)
  const unsigned short* wh0 = &wtL[(size_t)(n0 + l15) * 128 + lg * 8];
  const unsigned short* wh1 = &wtL[(size_t)(n0 + 16 + l15) * 128 + lg * 8];

  #pragma unroll
  for (int kt = 0; kt < 4; ++kt) {
    int k0 = kt * 32;
    short8 cbh0 = *(const short8*)(wh0 + k0);
    short8 cbh1 = *(const short8*)(wh1 + k0);
    short8 cbl0 = *(const short8*)(wh0 + 16384 + k0);
    short8 cbl1 = *(const short8*)(wh1 + 16384 + k0);
    #pragma unroll
    for (int rt = 0; rt < 4; ++rt) {
      float4 a0 = *(const float4*)(ap[rt] + k0);
      float4 a1 = *(const float4*)(ap[rt] + k0 + 4);
      unsigned int b0 = __float_as_uint(a0.x), b1 = __float_as_uint(a0.y);
      unsigned int b2 = __float_as_uint(a0.z), b3 = __float_as_uint(a0.w);
      unsigned int b4 = __float_as_uint(a1.x), b5 = __float_as_uint(a1.y);
      unsigned int b6 = __float_as_uint(a1.z), b7 = __float_as_uint(a1.w);
      unsigned int fh[4], fl[4];
      fh[0] = __builtin_amdgcn_perm(b1, b0, 0x07060302u);
      fh[1] = __builtin_amdgcn_perm(b3, b2, 0x07060302u);
      fh[2] = __builtin_amdgcn_perm(b5, b4, 0x07060302u);
      fh[3] = __builtin_amdgcn_perm(b7, b6, 0x07060302u);
      float r0 = a0.x - __uint_as_float(b0 & 0xFFFF0000u);
      float r1 = a0.y - __uint_as_float(b1 & 0xFFFF0000u);
      float r2 = a0.z - __uint_as_float(b2 & 0xFFFF0000u);
      float r3 = a0.w - __uint_as_float(b3 & 0xFFFF0000u);
      float r4 = a1.x - __uint_as_float(b4 & 0xFFFF0000u);
      float r5 = a1.y - __uint_as_float(b5 & 0xFFFF0000u);
      float r6 = a1.z - __uint_as_float(b6 & 0xFFFF0000u);
      float r7 = a1.w - __uint_as_float(b7 & 0xFFFF0000u);
      fl[0] = __builtin_amdgcn_perm(__float_as_uint(r1), __float_as_uint(r0), 0x07060302u);
      fl[1] = __builtin_amdgcn_perm(__float_as_uint(r3), __float_as_uint(r2), 0x07060302u);
      fl[2] = __builtin_amdgcn_perm(__float_as_uint(r5), __float_as_uint(r4), 0x07060302u);
      fl[3] = __builtin_amdgcn_perm(__float_as_uint(r7), __float_as_uint(r6), 0x07060302u);
      short8 fah = *(short8*)fh;
      short8 fal = *(short8*)fl;
      acc[rt][0] = __builtin_amdgcn_mfma_f32_16x16x32_bf16(fah, cbh0, acc[rt][0], 0, 0, 0);
      acc[rt][1] = __builtin_amdgcn_mfma_f32_16x16x32_bf16(fah, cbh1, acc[rt][1], 0, 0, 0);
      acc[rt][0] = __builtin_amdgcn_mfma_f32_16x16x32_bf16(fal, cbh0, acc[rt][0], 0, 0, 0);
      acc[rt][1] = __builtin_amdgcn_mfma_f32_16x16x32_bf16(fal, cbh1, acc[rt][1], 0, 0, 0);
      acc[rt][0] = __builtin_amdgcn_mfma_f32_16x16x32_bf16(fah, cbl0, acc[rt][0], 0, 0, 0);
      acc[rt][1] = __builtin_amdgcn_mfma_f32_16x16x32_bf16(fah, cbl1, acc[rt][1], 0, 0, 0);
    }
  }

  // ---- epilogue: h16 (pack adjacent cols via shfl) + exact attn logits ----
  int headg = ch * 2 + hd;
  float as0 = att_s[n0 + l15], as1 = att_s[n0 + 16 + l15];
  float ad0 = att_d[n0 + l15], ad1 = att_d[n0 + 16 + l15];
  #pragma unroll
  for (int rt = 0; rt < 4; ++rt) {
    float ps[4], pd[4];
    #pragma unroll
    for (int q = 0; q < 4; ++q) {
      float c0v = acc[rt][0][q], c1v = acc[rt][1][q];
      float p0 = __shfl_xor(c0v, 1), p1 = __shfl_xor(c1v, 1);
      int row = base + rh * 64 + rt * 16 + lg * 4 + q;
      if (!(l15 & 1) && row < N) {
        h16[(size_t)row * 64 + (n0 + l15) / 2]      = pack2(c0v, p0);
        h16[(size_t)row * 64 + (n0 + 16 + l15) / 2] = pack2(c1v, p1);
      }
      ps[q] = c0v * as0 + c1v * as1;
      pd[q] = c0v * ad0 + c1v * ad1;
    }
    #pragma unroll
    for (int m = 1; m <= 8; m <<= 1) {
      #pragma unroll
      for (int q = 0; q < 4; ++q) { ps[q] += __shfl_xor(ps[q], m); pd[q] += __shfl_xor(pd[q], m); }
    }
    if (l15 == 0) {
      #pragma unroll
      for (int q = 0; q < 4; ++q) {
        int row = base + rh * 64 + rt * 16 + lg * 4 + q;
        if (row < N) { a_s[row * 4 + headg] = ps[q]; a_d[row * 4 + headg] = pd[q]; }
      }
    }
  }
}

// ---------------- GAT aggregation, wave per dst node (R9 structure) ----------------

#define ACCP(EX, V0, V1)                                                       \
  { float2 ex2 = make_float2(EX, EX);                                          \
    acc2[0] += ex2 * make_float2(blo(V0.x), bhi(V0.x));                        \
    acc2[1] += ex2 * make_float2(blo(V0.y), bhi(V0.y));                        \
    acc2[2] += ex2 * make_float2(blo(V0.z), bhi(V0.z));                        \
    acc2[3] += ex2 * make_float2(blo(V0.w), bhi(V0.w));                        \
    acc2[4] += ex2 * make_float2(blo(V1.x), bhi(V1.x));                        \
    acc2[5] += ex2 * make_float2(blo(V1.y), bhi(V1.y));                        \
    acc2[6] += ex2 * make_float2(blo(V1.z), bhi(V1.z));                        \
    acc2[7] += ex2 * make_float2(blo(V1.w), bhi(V1.w)); }

__global__ __launch_bounds__(256) void gat_aggregate(
    const unsigned int* __restrict__ h16, const float* __restrict__ a_s, const float* __restrict__ a_d,
    const int* __restrict__ offsets, const int* __restrict__ counts, const int* __restrict__ ssrc,
    const float* __restrict__ bias,
    const float* __restrict__ bn_g, const float* __restrict__ bn_b,
    const float* __restrict__ bn_m, const float* __restrict__ bn_v,
    float* __restrict__ out, int N) {
  __shared__ float part[4][8][132];
  int wv = threadIdx.x >> 6;
  int lane = threadIdx.x & 63;
  int wid = blockIdx.x * 4 + wv;
  if (wid >= N) return;
  int off = offsets[wid], cnt = counts[wid];
  int eg = lane >> 3;          // edge group 0..7
  int j  = lane & 7;           // owns dims j*16 .. j*16+15
  int hh = j >> 1;             // head of those dims
  float ad = a_d[wid * 4 + hh];

  float2 acc2[8] = {};
  float den = 0.f;

  int sA = ssrc[off + (eg < cnt ? eg : 0)];
  int iB0 = eg + 8;
  int sB = ssrc[off + (iB0 < cnt ? iB0 : 0)];
  float asA = a_s[sA * 4 + hh];
  float asB = a_s[sB * 4 + hh];

  for (int i = eg; i < cnt; i += 16) {
    const uint4* hpA = (const uint4*)(h16 + (size_t)sA * 64 + j * 8);
    uint4 va0 = hpA[0], va1 = hpA[1];
    const uint4* hpB = (const uint4*)(h16 + (size_t)sB * 64 + j * 8);
    uint4 vb0 = hpB[0], vb1 = hpB[1];
    int in0 = i + 16, in1 = i + 24;
    int snA = ssrc[off + (in0 < cnt ? in0 : 0)];
    int snB = ssrc[off + (in1 < cnt ? in1 : 0)];
    float anA = a_s[snA * 4 + hh];
    float anB = a_s[snB * 4 + hh];
    float eA = asA + ad; eA = eA > 0.f ? eA : 0.2f * eA;
    float exA = __expf(eA);
    float eB = asB + ad; eB = eB > 0.f ? eB : 0.2f * eB;
    float exB = ((i + 8) < cnt) ? __expf(eB) : 0.f;
    den += exA + exB;
    ACCP(exA, va0, va1)
    ACCP(exB, vb0, vb1)
    sA = snA; sB = snB; asA = anA; asB = anB;
  }

  den += __shfl_xor(den, 8);
  den += __shfl_xor(den, 16);
  den += __shfl_xor(den, 32);
  den = __shfl(den, (lane >> 4) * 2);

  float* pw = &part[wv][eg][j * 16];
  *(float4*)(pw + 0)  = make_float4(acc2[0].x, acc2[0].y, acc2[1].x, acc2[1].y);
  *(float4*)(pw + 4)  = make_float4(acc2[2].x, acc2[2].y, acc2[3].x, acc2[3].y);
  *(float4*)(pw + 8)  = make_float4(acc2[4].x, acc2[4].y, acc2[5].x, acc2[5].y);
  *(float4*)(pw + 12) = make_float4(acc2[6].x, acc2[6].y, acc2[7].x, acc2[7].y);
  asm volatile("s_waitcnt lgkmcnt(0)" ::: "memory");

  int d = lane * 2;
  float r0 = 0.f, r1 = 0.f;
  #pragma unroll
  for (int g = 0; g < 8; ++g) {
    float2 v = *(const float2*)(&part[wv][g][d]);
    r0 += v.x; r1 += v.y;
  }

  float inv = 1.f / (den + 1e-16f);
  float2 bi = *(const float2*)(&bias[d]);
  float2 g2 = *(const float2*)(&bn_g[d]);
  float2 b2 = *(const float2*)(&bn_b[d]);
  float2 m2 = *(const float2*)(&bn_m[d]);
  float2 v2 = *(const float2*)(&bn_v[d]);
  float o0 = r0 * inv + bi.x;
  float o1 = r1 * inv + bi.y;
  o0 = fmaxf((o0 - m2.x) * (g2.x * rsqrtf(v2.x + 1e-5f)) + b2.x, 0.f);
  o1 = fmaxf((o1 - m2.y) * (g2.y * rsqrtf(v2.y + 1e-5f)) + b2.y, 0.f);
  *(float2*)(&out[(size_t)wid * 128 + d]) = make_float2(o0, o1);
}

// ---------------- global mean pool (partial) + head MLP ----------------

#define POOLP 8

__global__ __launch_bounds__(256) void pool_kernel(const float* __restrict__ y,
                                                   const int* __restrict__ go,
                                                   const int* __restrict__ ge,
                                                   float* __restrict__ pooled) {
  int g = blockIdx.x / POOLP, p = blockIdx.x % POOLP;
  int s = go[g], e = ge[g];
  int len = e - s;
  int q0 = s + (len * p) / POOLP, q1 = s + (len * (p + 1)) / POOLP;
  int t = threadIdx.x;
  int d = t & 127, half = t >> 7;
  float acc = 0.f;
  for (int i = q0 + half; i < q1; i += 2) acc += y[(size_t)i * 128 + d];
  __shared__ float red[256];
  red[t] = acc;
  __syncthreads();
  if (half == 0) atomicAdd(&pooled[g * 128 + d], red[d] + red[d + 128]);
}

__global__ __launch_bounds__(64) void mlp_kernel(const float* __restrict__ pooled,
                                                 const int* __restrict__ go,
                                                 const int* __restrict__ ge,
                                                 const float* __restrict__ w1,
                                                 const float* __restrict__ b1,
                                                 const float* __restrict__ w2,
                                                 const float* __restrict__ b2,
                                                 float* __restrict__ out) {
  int g = blockIdx.x, j = threadIdx.x;
  int cnt = ge[g] - go[g];
  float inv = 1.f / (float)(cnt > 1 ? cnt : 1);
  float z = b1[j];
  for (int k = 0; k < 128; ++k) z += pooled[g * 128 + k] * inv * w1[k * 64 + j];
  z = fmaxf(z, 0.f);
  float v = z * w2[j];
  #pragma unroll
  for (int m = 1; m < 64; m <<= 1) v += __shfl_xor(v, m);
  if (j == 0) out[g] = v + b2[0];
}

// ---------------- launch ----------------

extern "C" void kernel_launch(void* const* d_in, const int* in_sizes, int n_in,
                              void* d_out, int out_size, void* d_ws, size_t ws_size,
                              hipStream_t stream) {
  const float* x     = (const float*)d_in[0];
  const int*   ei    = (const int*)d_in[1];
  const int*   batch = (const int*)d_in[2];
  const float* w0    = (const float*)d_in[3];
  const float* atts0 = (const float*)d_in[4];
  const float* attd0 = (const float*)d_in[5];
  const float* bias0 = (const float*)d_in[6];
  const float* w1    = (const float*)d_in[7];
  const float* atts1 = (const float*)d_in[8];
  const float* attd1 = (const float*)d_in[9];
  const float* bias1 = (const float*)d_in[10];
  const float* bng0  = (const float*)d_in[11];
  const float* bnb0  = (const float*)d_in[12];
  const float* bnm0  = (const float*)d_in[13];
  const float* bnv0  = (const float*)d_in[14];
  const float* bng1  = (const float*)d_in[15];
  const float* bnb1  = (const float*)d_in[16];
  const float* bnm1  = (const float*)d_in[17];
  const float* bnv1  = (const float*)d_in[18];
  const float* l1w   = (const float*)d_in[19];
  const float* l1b   = (const float*)d_in[20];
  const float* l2w   = (const float*)d_in[21];
  const float* l2b   = (const float*)d_in[22];

  int N = in_sizes[2];        // batch length
  int E = in_sizes[1] / 2;    // edge_index is [2,E]
  int tot = E + N;
  int NBIN = (N + 511) / 512;

  char* p = (char*)d_ws;
  unsigned int* h16 = (unsigned int*)p; p += (size_t)N * 128 * 2;  // bf16 payload
  float* y_buf  = (float*)p; p += (size_t)N * 128 * 4;
  float* a_s    = (float*)p; p += (size_t)N * 4 * 4;
  float* a_d    = (float*)p; p += (size_t)N * 4 * 4;
  int* counts   = (int*)p;   p += (size_t)N * 4;
  int* offsets  = (int*)p;   p += (size_t)N * 4;
  int* ssrc     = (int*)p;   p += (size_t)NBINMAX * STRIDE * 4;
  int* gcur     = (int*)p;   p += NBINMAX * 4;
  int* gstart   = (int*)p;   p += 64 * 4;
  int* go       = (int*)p;   p += 64 * 4;
  int* ge       = (int*)p;   p += 64 * 4;
  float* pooled = (float*)p; p += 64 * 128 * 4;
  unsigned short* wt = (unsigned short*)p; p += 2 * 32768 * 2;  // [2][hi/lo][n][k]
  // pairs buffer aliases y_buf (dead before y_buf is first written)
  unsigned int* pairs = (unsigned int*)y_buf;

  hipMemsetAsync(gstart, 0xFF, 64 * 4, stream);
  hipMemsetAsync(pooled, 0, 64 * 128 * 4, stream);

  int bN = (N + 255) / 256;
  int bW = (N + 3) / 4;              // wave-per-node kernels
  int bG2 = 2 * ((N + 127) / 128);   // gemm: row tiles x 2 col-halves

  wprep<<<128, 256, 0, stream>>>(w0, w1, wt, gcur);   // also inits gcur
  part_p1<<<(tot + 4095) / 4096, 256, 0, stream>>>(ei, gcur, pairs, E, N);
  part_p2<<<NBIN, 256, 0, stream>>>(pairs, gcur, ssrc, offsets, counts, N);
  gbounds<<<bN, 256, 0, stream>>>(batch, gstart, N);
  gfix<<<1, 64, 0, stream>>>(gstart, go, ge, N);

  // layer 0
  gemm_mfma<<<bG2, 256, 0, stream>>>(x, wt, atts0, attd0, h16, a_s, a_d, N);
  gat_aggregate<<<bW, 256, 0, stream>>>(h16, a_s, a_d, offsets, counts, ssrc,
                                        bias0, bng0, bnb0, bnm0, bnv0, y_buf, N);
  // layer 1
  gemm_mfma<<<bG2, 256, 0, stream>>>(y_buf, wt + 32768, atts1, attd1, h16, a_s, a_d, N);
  gat_aggregate<<<bW, 256, 0, stream>>>(h16, a_s, a_d, offsets, counts, ssrc,
                                        bias1, bng1, bnb1, bnm1, bnv1, y_buf, N);
  // pool + head
  pool_kernel<<<GG * POOLP, 256, 0, stream>>>(y_buf, go, ge, pooled);
  mlp_kernel<<<GG, 64, 0, stream>>>(pooled, go, ge, l1w, l1b, l2w, l2b, (float*)d_out);
}

// Round 15
// 324.075 us; speedup vs baseline: 1.0951x; 1.0951x over previous
//
#include <hip/hip_runtime.h>

#define GG 64        // graphs
#define STRIDE 10240 // per-bin region capacity (mean 8704 -> big headroom)
#define NBINMAX 256  // bins = dst>>9, N<=131072

typedef __attribute__((ext_vector_type(8))) short short8;   // 8 bf16 (4 VGPR)
typedef __attribute__((ext_vector_type(4))) float f32x4;    // 4 fp32 acc

// ---------------- bf16 helpers ----------------

__device__ inline unsigned short bf16rne(float f) {
  unsigned int x = __float_as_uint(f);
  unsigned int r = (x + 0x7FFFu + ((x >> 16) & 1u)) >> 16;
  return (unsigned short)r;
}
__device__ inline unsigned int pack2(float a, float b) {
  return (unsigned int)bf16rne(a) | ((unsigned int)bf16rne(b) << 16);
}
__device__ inline float blo(unsigned int v) { return __uint_as_float(v << 16); }
__device__ inline float bhi(unsigned int v) { return __uint_as_float(v & 0xFFFF0000u); }

// ---------------- edge partition, level 1: coarse bins ----------------

__global__ __launch_bounds__(256) void part_p1(const int* __restrict__ ei,
                                               int* __restrict__ gcur,
                                               unsigned int* __restrict__ pairs,
                                               int E, int N) {
  __shared__ int hist[NBINMAX];
  __shared__ int gbase[NBINMAX];
  __shared__ int lcur[NBINMAX];
  int t = threadIdx.x;
  int tot = E + N;
  int base = blockIdx.x * 4096;
  hist[t] = 0;
  __syncthreads();
  int sarr[16], darr[16];
  #pragma unroll
  for (int k = 0; k < 16; ++k) {
    int i = base + k * 256 + t;
    if (i < tot) {
      int s, d;
      if (i < E) { s = ei[i]; d = ei[E + i]; } else { s = i - E; d = s; }
      sarr[k] = s; darr[k] = d;
      atomicAdd(&hist[d >> 9], 1);
    } else darr[k] = -1;
  }
  __syncthreads();
  int c = hist[t];
  gbase[t] = (c > 0) ? atomicAdd(&gcur[t], c) : 0;
  lcur[t] = 0;
  __syncthreads();
  #pragma unroll
  for (int k = 0; k < 16; ++k) {
    int d = darr[k];
    if (d >= 0) {
      int b = d >> 9;
      int p = gbase[b] + atomicAdd(&lcur[b], 1);
      pairs[p] = ((unsigned int)(d & 511) << 17) | (unsigned int)sarr[k];
    }
  }
}

// ---------------- edge partition, level 2: exact CSR within bin ----------------

__global__ __launch_bounds__(256) void part_p2(const unsigned int* __restrict__ pairs,
                                               const int* __restrict__ gcur,
                                               int* __restrict__ ssrc,
                                               int* __restrict__ offsets,
                                               int* __restrict__ counts, int N) {
  __shared__ int ncnt[512], ncur[512], excl_s[512];
  __shared__ int wsum[4];
  int b = blockIdx.x;
  int t = threadIdx.x;
  int pb = b * STRIDE;
  int cnt = gcur[b] - pb;
  ncnt[t] = 0; ncnt[t + 256] = 0;
  __syncthreads();
  for (int e = t; e < cnt; e += 256) {
    unsigned int v = pairs[pb + e];
    atomicAdd(&ncnt[v >> 17], 1);
  }
  __syncthreads();
  int c0 = ncnt[2 * t], c1 = ncnt[2 * t + 1];
  int ps = c0 + c1;
  int lane = t & 63, w = t >> 6;
  int x = ps;
  #pragma unroll
  for (int s = 1; s < 64; s <<= 1) { int y = __shfl_up(x, s); if (lane >= s) x += y; }
  if (lane == 63) wsum[w] = x;
  __syncthreads();
  int woff = 0;
  for (int i = 0; i < w; ++i) woff += wsum[i];
  int ep = woff + x - ps;
  excl_s[2 * t]     = ep;
  excl_s[2 * t + 1] = ep + c0;
  __syncthreads();
  int binstart = b << 9;
  for (int i = t; i < 512; i += 256) {
    ncur[i] = excl_s[i];
    int node = binstart + i;
    if (node < N) { offsets[node] = pb + excl_s[i]; counts[node] = ncnt[i]; }
  }
  __syncthreads();
  for (int e = t; e < cnt; e += 256) {
    unsigned int v = pairs[pb + e];
    int dl = v >> 17;
    int p = atomicAdd(&ncur[dl], 1);
    ssrc[pb + p] = (int)(v & 0x1FFFF);
  }
}

// ---------------- graph boundaries (batch is sorted) ----------------

__global__ __launch_bounds__(256) void gbounds(const int* __restrict__ batch,
                                               int* __restrict__ gstart, int N) {
  int i = blockIdx.x * 256 + threadIdx.x;
  if (i >= N) return;
  int g = batch[i];
  if (i == 0 || batch[i - 1] != g) gstart[g] = i;
}

// wave-parallel: suffix-min of valid starts gives each graph's end
__global__ __launch_bounds__(64) void gfix(const int* __restrict__ gstart,
                                           int* __restrict__ go,
                                           int* __restrict__ ge, int N) {
  int g = threadIdx.x;                 // 64 lanes = 64 graphs
  int s = gstart[g];
  int v = (s < 0) ? 0x7FFFFFFF : s;
  int suf = v;
  #pragma unroll
  for (int off = 1; off < 64; off <<= 1) {
    int x = __shfl_down(suf, off);
    if (g + off < 64) suf = min(suf, x);
  }
  int nxt = __shfl_down(suf, 1);       // suffix-min over lanes > g
  if (g == 63) nxt = 0x7FFFFFFF;
  int e = nxt == 0x7FFFFFFF ? N : nxt;
  if (s < 0) { go[g] = e; ge[g] = e; }
  else       { go[g] = s; ge[g] = e; }
}

// ---------------- prep: weight transpose/split + gcur init ----------------

__global__ __launch_bounds__(256) void wprep(const float* __restrict__ w0,
                                             const float* __restrict__ w1,
                                             unsigned short* __restrict__ wt,
                                             int* __restrict__ gcur) {
  if (blockIdx.x == 0) gcur[threadIdx.x] = threadIdx.x * STRIDE;
  int idx = blockIdx.x * 256 + threadIdx.x;   // 0..32767
  int layer = idx >> 14;
  int e = idx & 16383;
  int k = e >> 7, n = e & 127;
  float v = (layer ? w1 : w0)[e];
  unsigned short hi = bf16rne(v);
  float hif = __uint_as_float((unsigned int)hi << 16);
  unsigned short lo = bf16rne(v - hif);
  unsigned short* basep = wt + layer * 32768;
  basep[n * 128 + k] = hi;
  basep[16384 + n * 128 + k] = lo;
}

// ---------------- MFMA bf16-split GEMM [N,128]@[128,128] + attn logits ----
// R13-proven structure: column-split grid (block = 128 rows x 64 cols);
// wave w: head w&1, row-half w>>1. LDS stages x once per block (traffic
// de-dup — R14's LDS-free variant read x 4x and regressed). x staged via
// truncation split (xh = hi16(v) via v_perm, r = v - (v&0xffff0000) exact,
// xl = hi16(r)). B-frags from L2-hot pre-split weights. Pipelined prefetch.

__global__ __launch_bounds__(256) void gemm_mfma(
    const float* __restrict__ in, const unsigned short* __restrict__ wtL,
    const float* __restrict__ att_s, const float* __restrict__ att_d,
    unsigned int* __restrict__ h16, float* __restrict__ a_s,
    float* __restrict__ a_d, int N) {
  __shared__ unsigned short xh[128][40], xl[128][40];   // [row][k] bf16 hi/lo
  int t = threadIdx.x;
  int bid = blockIdx.x;
  int ch = bid & 1;               // column half (heads 2ch, 2ch+1)
  int base = (bid >> 1) * 128;    // row base
  int lane = t & 63, w = t >> 6;
  int l15 = lane & 15, lg = lane >> 4;
  int hd = w & 1;                 // head within this col-half
  int n0 = ch * 64 + hd * 32;     // global col base for this wave
  int rh = w >> 1;                // row half (0: rows 0-63, 1: 64-127)

  f32x4 zero4 = {0.f, 0.f, 0.f, 0.f};
  f32x4 acc[4][2];
  #pragma unroll
  for (int rt = 0; rt < 4; ++rt) { acc[rt][0] = zero4; acc[rt][1] = zero4; }

  // x staging assignment: thread stages row sr, k-half sc
  int sr = t >> 1;
  int sc = (t & 1) * 16;
  int gr = base + sr;
  int rc = gr < N ? gr : (N - 1);
  const float* xp = &in[(size_t)rc * 128 + sc];

  // B-frag row pointers (ushort elements; +16384 = lo plane)
  const unsigned short* wh0 = &wtL[(size_t)(n0 + l15) * 128];
  const unsigned short* wh1 = &wtL[(size_t)(n0 + 16 + l15) * 128];

  // prologue: preload kt=0 x tile and B frags
  float4 u0 = *(const float4*)(xp + 0);
  float4 u1 = *(const float4*)(xp + 4);
  float4 u2 = *(const float4*)(xp + 8);
  float4 u3 = *(const float4*)(xp + 12);
  short8 cbh0 = *(const short8*)(wh0 + lg * 8);
  short8 cbh1 = *(const short8*)(wh1 + lg * 8);
  short8 cbl0 = *(const short8*)(wh0 + 16384 + lg * 8);
  short8 cbl1 = *(const short8*)(wh1 + 16384 + lg * 8);

  #pragma unroll
  for (int kt = 0; kt < 4; ++kt) {
    if (kt) __syncthreads();   // prev iteration's LDS reads complete
    // convert + write this tile's x into LDS (truncation split)
    {
      float4 uu[4] = {u0, u1, u2, u3};
      #pragma unroll
      for (int q = 0; q < 4; ++q) {
        float4 u = uu[q];
        unsigned int b0 = __float_as_uint(u.x), b1 = __float_as_uint(u.y);
        unsigned int b2 = __float_as_uint(u.z), b3 = __float_as_uint(u.w);
        *(unsigned int*)&xh[sr][sc + q * 4]     = __builtin_amdgcn_perm(b1, b0, 0x07060302u);
        *(unsigned int*)&xh[sr][sc + q * 4 + 2] = __builtin_amdgcn_perm(b3, b2, 0x07060302u);
        float r0 = u.x - __uint_as_float(b0 & 0xFFFF0000u);
        float r1 = u.y - __uint_as_float(b1 & 0xFFFF0000u);
        float r2 = u.z - __uint_as_float(b2 & 0xFFFF0000u);
        float r3 = u.w - __uint_as_float(b3 & 0xFFFF0000u);
        *(unsigned int*)&xl[sr][sc + q * 4] =
            __builtin_amdgcn_perm(__float_as_uint(r1), __float_as_uint(r0), 0x07060302u);
        *(unsigned int*)&xl[sr][sc + q * 4 + 2] =
            __builtin_amdgcn_perm(__float_as_uint(r3), __float_as_uint(r2), 0x07060302u);
      }
    }
    __syncthreads();           // LDS tile ready
    // prefetch next tile (x regs + B frags) — hidden under MFMA below
    float4 v0 = u0, v1 = u1, v2 = u2, v3 = u3;
    short8 nbh0 = cbh0, nbh1 = cbh1, nbl0 = cbl0, nbl1 = cbl1;
    if (kt < 3) {
      int k1 = (kt + 1) * 32;
      v0 = *(const float4*)(xp + k1);
      v1 = *(const float4*)(xp + k1 + 4);
      v2 = *(const float4*)(xp + k1 + 8);
      v3 = *(const float4*)(xp + k1 + 12);
      nbh0 = *(const short8*)(wh0 + k1 + lg * 8);
      nbh1 = *(const short8*)(wh1 + k1 + lg * 8);
      nbl0 = *(const short8*)(wh0 + 16384 + k1 + lg * 8);
      nbl1 = *(const short8*)(wh1 + 16384 + k1 + lg * 8);
    }
    // A-frags + MFMA (rows rh*64 + rt*16 + l15)
    #pragma unroll
    for (int rt = 0; rt < 4; ++rt) {
      int row = rh * 64 + rt * 16 + l15;
      short8 fah = *(const short8*)&xh[row][lg * 8];
      short8 fal = *(const short8*)&xl[row][lg * 8];
      acc[rt][0] = __builtin_amdgcn_mfma_f32_16x16x32_bf16(fah, cbh0, acc[rt][0], 0, 0, 0);
      acc[rt][1] = __builtin_amdgcn_mfma_f32_16x16x32_bf16(fah, cbh1, acc[rt][1], 0, 0, 0);
      acc[rt][0] = __builtin_amdgcn_mfma_f32_16x16x32_bf16(fal, cbh0, acc[rt][0], 0, 0, 0);
      acc[rt][1] = __builtin_amdgcn_mfma_f32_16x16x32_bf16(fal, cbh1, acc[rt][1], 0, 0, 0);
      acc[rt][0] = __builtin_amdgcn_mfma_f32_16x16x32_bf16(fah, cbl0, acc[rt][0], 0, 0, 0);
      acc[rt][1] = __builtin_amdgcn_mfma_f32_16x16x32_bf16(fah, cbl1, acc[rt][1], 0, 0, 0);
    }
    u0 = v0; u1 = v1; u2 = v2; u3 = v3;
    cbh0 = nbh0; cbh1 = nbh1; cbl0 = nbl0; cbl1 = nbl1;
  }

  // ---- epilogue: h16 (pack adjacent cols via shfl) + exact attn logits ----
  int headg = ch * 2 + hd;
  float as0 = att_s[n0 + l15], as1 = att_s[n0 + 16 + l15];
  float ad0 = att_d[n0 + l15], ad1 = att_d[n0 + 16 + l15];
  #pragma unroll
  for (int rt = 0; rt < 4; ++rt) {
    float ps[4], pd[4];
    #pragma unroll
    for (int q = 0; q < 4; ++q) {
      float c0v = acc[rt][0][q], c1v = acc[rt][1][q];
      float p0 = __shfl_xor(c0v, 1), p1 = __shfl_xor(c1v, 1);
      int row = base + rh * 64 + rt * 16 + lg * 4 + q;
      if (!(l15 & 1) && row < N) {
        h16[(size_t)row * 64 + (n0 + l15) / 2]      = pack2(c0v, p0);
        h16[(size_t)row * 64 + (n0 + 16 + l15) / 2] = pack2(c1v, p1);
      }
      ps[q] = c0v * as0 + c1v * as1;
      pd[q] = c0v * ad0 + c1v * ad1;
    }
    #pragma unroll
    for (int m = 1; m <= 8; m <<= 1) {
      #pragma unroll
      for (int q = 0; q < 4; ++q) { ps[q] += __shfl_xor(ps[q], m); pd[q] += __shfl_xor(pd[q], m); }
    }
    if (l15 == 0) {
      #pragma unroll
      for (int q = 0; q < 4; ++q) {
        int row = base + rh * 64 + rt * 16 + lg * 4 + q;
        if (row < N) { a_s[row * 4 + headg] = ps[q]; a_d[row * 4 + headg] = pd[q]; }
      }
    }
  }
}

// ---------------- GAT aggregation, wave per dst node (R9 structure) ----------------

#define ACCP(EX, V0, V1)                                                       \
  { float2 ex2 = make_float2(EX, EX);                                          \
    acc2[0] += ex2 * make_float2(blo(V0.x), bhi(V0.x));                        \
    acc2[1] += ex2 * make_float2(blo(V0.y), bhi(V0.y));                        \
    acc2[2] += ex2 * make_float2(blo(V0.z), bhi(V0.z));                        \
    acc2[3] += ex2 * make_float2(blo(V0.w), bhi(V0.w));                        \
    acc2[4] += ex2 * make_float2(blo(V1.x), bhi(V1.x));                        \
    acc2[5] += ex2 * make_float2(blo(V1.y), bhi(V1.y));                        \
    acc2[6] += ex2 * make_float2(blo(V1.z), bhi(V1.z));                        \
    acc2[7] += ex2 * make_float2(blo(V1.w), bhi(V1.w)); }

__global__ __launch_bounds__(256) void gat_aggregate(
    const unsigned int* __restrict__ h16, const float* __restrict__ a_s, const float* __restrict__ a_d,
    const int* __restrict__ offsets, const int* __restrict__ counts, const int* __restrict__ ssrc,
    const float* __restrict__ bias,
    const float* __restrict__ bn_g, const float* __restrict__ bn_b,
    const float* __restrict__ bn_m, const float* __restrict__ bn_v,
    float* __restrict__ out, int N) {
  __shared__ float part[4][8][132];
  int wv = threadIdx.x >> 6;
  int lane = threadIdx.x & 63;
  int wid = blockIdx.x * 4 + wv;
  if (wid >= N) return;
  int off = offsets[wid], cnt = counts[wid];
  int eg = lane >> 3;          // edge group 0..7
  int j  = lane & 7;           // owns dims j*16 .. j*16+15
  int hh = j >> 1;             // head of those dims
  float ad = a_d[wid * 4 + hh];

  float2 acc2[8] = {};
  float den = 0.f;

  int sA = ssrc[off + (eg < cnt ? eg : 0)];
  int iB0 = eg + 8;
  int sB = ssrc[off + (iB0 < cnt ? iB0 : 0)];
  float asA = a_s[sA * 4 + hh];
  float asB = a_s[sB * 4 + hh];

  for (int i = eg; i < cnt; i += 16) {
    const uint4* hpA = (const uint4*)(h16 + (size_t)sA * 64 + j * 8);
    uint4 va0 = hpA[0], va1 = hpA[1];
    const uint4* hpB = (const uint4*)(h16 + (size_t)sB * 64 + j * 8);
    uint4 vb0 = hpB[0], vb1 = hpB[1];
    int in0 = i + 16, in1 = i + 24;
    int snA = ssrc[off + (in0 < cnt ? in0 : 0)];
    int snB = ssrc[off + (in1 < cnt ? in1 : 0)];
    float anA = a_s[snA * 4 + hh];
    float anB = a_s[snB * 4 + hh];
    float eA = asA + ad; eA = eA > 0.f ? eA : 0.2f * eA;
    float exA = __expf(eA);
    float eB = asB + ad; eB = eB > 0.f ? eB : 0.2f * eB;
    float exB = ((i + 8) < cnt) ? __expf(eB) : 0.f;
    den += exA + exB;
    ACCP(exA, va0, va1)
    ACCP(exB, vb0, vb1)
    sA = snA; sB = snB; asA = anA; asB = anB;
  }

  den += __shfl_xor(den, 8);
  den += __shfl_xor(den, 16);
  den += __shfl_xor(den, 32);
  den = __shfl(den, (lane >> 4) * 2);

  float* pw = &part[wv][eg][j * 16];
  *(float4*)(pw + 0)  = make_float4(acc2[0].x, acc2[0].y, acc2[1].x, acc2[1].y);
  *(float4*)(pw + 4)  = make_float4(acc2[2].x, acc2[2].y, acc2[3].x, acc2[3].y);
  *(float4*)(pw + 8)  = make_float4(acc2[4].x, acc2[4].y, acc2[5].x, acc2[5].y);
  *(float4*)(pw + 12) = make_float4(acc2[6].x, acc2[6].y, acc2[7].x, acc2[7].y);
  asm volatile("s_waitcnt lgkmcnt(0)" ::: "memory");

  int d = lane * 2;
  float r0 = 0.f, r1 = 0.f;
  #pragma unroll
  for (int g = 0; g < 8; ++g) {
    float2 v = *(const float2*)(&part[wv][g][d]);
    r0 += v.x; r1 += v.y;
  }

  float inv = 1.f / (den + 1e-16f);
  float2 bi = *(const float2*)(&bias[d]);
  float2 g2 = *(const float2*)(&bn_g[d]);
  float2 b2 = *(const float2*)(&bn_b[d]);
  float2 m2 = *(const float2*)(&bn_m[d]);
  float2 v2 = *(const float2*)(&bn_v[d]);
  float o0 = r0 * inv + bi.x;
  float o1 = r1 * inv + bi.y;
  o0 = fmaxf((o0 - m2.x) * (g2.x * rsqrtf(v2.x + 1e-5f)) + b2.x, 0.f);
  o1 = fmaxf((o1 - m2.y) * (g2.y * rsqrtf(v2.y + 1e-5f)) + b2.y, 0.f);
  *(float2*)(&out[(size_t)wid * 128 + d]) = make_float2(o0, o1);
}

// ---------------- global mean pool (partial) + head MLP ----------------

#define POOLP 8

__global__ __launch_bounds__(256) void pool_kernel(const float* __restrict__ y,
                                                   const int* __restrict__ go,
                                                   const int* __restrict__ ge,
                                                   float* __restrict__ pooled) {
  int g = blockIdx.x / POOLP, p = blockIdx.x % POOLP;
  int s = go[g], e = ge[g];
  int len = e - s;
  int q0 = s + (len * p) / POOLP, q1 = s + (len * (p + 1)) / POOLP;
  int t = threadIdx.x;
  int d = t & 127, half = t >> 7;
  float acc = 0.f;
  for (int i = q0 + half; i < q1; i += 2) acc += y[(size_t)i * 128 + d];
  __shared__ float red[256];
  red[t] = acc;
  __syncthreads();
  if (half == 0) atomicAdd(&pooled[g * 128 + d], red[d] + red[d + 128]);
}

__global__ __launch_bounds__(64) void mlp_kernel(const float* __restrict__ pooled,
                                                 const int* __restrict__ go,
                                                 const int* __restrict__ ge,
                                                 const float* __restrict__ w1,
                                                 const float* __restrict__ b1,
                                                 const float* __restrict__ w2,
                                                 const float* __restrict__ b2,
                                                 float* __restrict__ out) {
  int g = blockIdx.x, j = threadIdx.x;
  int cnt = ge[g] - go[g];
  float inv = 1.f / (float)(cnt > 1 ? cnt : 1);
  float z = b1[j];
  for (int k = 0; k < 128; ++k) z += pooled[g * 128 + k] * inv * w1[k * 64 + j];
  z = fmaxf(z, 0.f);
  float v = z * w2[j];
  #pragma unroll
  for (int m = 1; m < 64; m <<= 1) v += __shfl_xor(v, m);
  if (j == 0) out[g] = v + b2[0];
}

// ---------------- launch ----------------

extern "C" void kernel_launch(void* const* d_in, const int* in_sizes, int n_in,
                              void* d_out, int out_size, void* d_ws, size_t ws_size,
                              hipStream_t stream) {
  const float* x     = (const float*)d_in[0];
  const int*   ei    = (const int*)d_in[1];
  const int*   batch = (const int*)d_in[2];
  const float* w0    = (const float*)d_in[3];
  const float* atts0 = (const float*)d_in[4];
  const float* attd0 = (const float*)d_in[5];
  const float* bias0 = (const float*)d_in[6];
  const float* w1    = (const float*)d_in[7];
  const float* atts1 = (const float*)d_in[8];
  const float* attd1 = (const float*)d_in[9];
  const float* bias1 = (const float*)d_in[10];
  const float* bng0  = (const float*)d_in[11];
  const float* bnb0  = (const float*)d_in[12];
  const float* bnm0  = (const float*)d_in[13];
  const float* bnv0  = (const float*)d_in[14];
  const float* bng1  = (const float*)d_in[15];
  const float* bnb1  = (const float*)d_in[16];
  const float* bnm1  = (const float*)d_in[17];
  const float* bnv1  = (const float*)d_in[18];
  const float* l1w   = (const float*)d_in[19];
  const float* l1b   = (const float*)d_in[20];
  const float* l2w   = (const float*)d_in[21];
  const float* l2b   = (const float*)d_in[22];

  int N = in_sizes[2];        // batch length
  int E = in_sizes[1] / 2;    // edge_index is [2,E]
  int tot = E + N;
  int NBIN = (N + 511) / 512;

  char* p = (char*)d_ws;
  unsigned int* h16 = (unsigned int*)p; p += (size_t)N * 128 * 2;  // bf16 payload
  float* y_buf  = (float*)p; p += (size_t)N * 128 * 4;
  float* a_s    = (float*)p; p += (size_t)N * 4 * 4;
  float* a_d    = (float*)p; p += (size_t)N * 4 * 4;
  int* counts   = (int*)p;   p += (size_t)N * 4;
  int* offsets  = (int*)p;   p += (size_t)N * 4;
  int* ssrc     = (int*)p;   p += (size_t)NBINMAX * STRIDE * 4;
  int* gcur     = (int*)p;   p += NBINMAX * 4;
  int* gstart   = (int*)p;   p += 64 * 4;
  int* go       = (int*)p;   p += 64 * 4;
  int* ge       = (int*)p;   p += 64 * 4;
  float* pooled = (float*)p; p += 64 * 128 * 4;
  unsigned short* wt = (unsigned short*)p; p += 2 * 32768 * 2;  // [2][hi/lo][n][k]
  // pairs buffer aliases y_buf (dead before y_buf is first written)
  unsigned int* pairs = (unsigned int*)y_buf;

  hipMemsetAsync(gstart, 0xFF, 64 * 4, stream);
  hipMemsetAsync(pooled, 0, 64 * 128 * 4, stream);

  int bN = (N + 255) / 256;
  int bW = (N + 3) / 4;              // wave-per-node kernels
  int bG2 = 2 * ((N + 127) / 128);   // gemm: row tiles x 2 col-halves

  wprep<<<128, 256, 0, stream>>>(w0, w1, wt, gcur);   // also inits gcur
  part_p1<<<(tot + 4095) / 4096, 256, 0, stream>>>(ei, gcur, pairs, E, N);
  part_p2<<<NBIN, 256, 0, stream>>>(pairs, gcur, ssrc, offsets, counts, N);
  gbounds<<<bN, 256, 0, stream>>>(batch, gstart, N);
  gfix<<<1, 64, 0, stream>>>(gstart, go, ge, N);

  // layer 0
  gemm_mfma<<<bG2, 256, 0, stream>>>(x, wt, atts0, attd0, h16, a_s, a_d, N);
  gat_aggregate<<<bW, 256, 0, stream>>>(h16, a_s, a_d, offsets, counts, ssrc,
                                        bias0, bng0, bnb0, bnm0, bnv0, y_buf, N);
  // layer 1
  gemm_mfma<<<bG2, 256, 0, stream>>>(y_buf, wt + 32768, atts1, attd1, h16, a_s, a_d, N);
  gat_aggregate<<<bW, 256, 0, stream>>>(h16, a_s, a_d, offsets, counts, ssrc,
                                        bias1, bng1, bnb1, bnm1, bnv1, y_buf, N);
  // pool + head
  pool_kernel<<<GG * POOLP, 256, 0, stream>>>(y_buf, go, ge, pooled);
  mlp_kernel<<<GG, 64, 0, stream>>>(pooled, go, ge, l1w, l1b, l2w, l2b, (float*)d_out);
}

// Round 16
// 312.734 us; speedup vs baseline: 1.1348x; 1.0363x over previous
//
#include <hip/hip_runtime.h>

#define GG 64        // graphs
#define STRIDE 10240 // per-bin region capacity (mean 8704 -> big headroom)
#define NBINMAX 256  // bins = dst>>9, N<=131072

typedef __attribute__((ext_vector_type(8))) short short8;   // 8 bf16 (4 VGPR)
typedef __attribute__((ext_vector_type(4))) float f32x4;    // 4 fp32 acc

// ---------------- bf16 helpers ----------------

__device__ inline unsigned short bf16rne(float f) {
  unsigned int x = __float_as_uint(f);
  unsigned int r = (x + 0x7FFFu + ((x >> 16) & 1u)) >> 16;
  return (unsigned short)r;
}
__device__ inline unsigned int pack2(float a, float b) {
  return (unsigned int)bf16rne(a) | ((unsigned int)bf16rne(b) << 16);
}
__device__ inline float blo(unsigned int v) { return __uint_as_float(v << 16); }
__device__ inline float bhi(unsigned int v) { return __uint_as_float(v & 0xFFFF0000u); }

// ---------------- edge partition, level 1: coarse bins ----------------

__global__ __launch_bounds__(256) void part_p1(const int* __restrict__ ei,
                                               int* __restrict__ gcur,
                                               unsigned int* __restrict__ pairs,
                                               int E, int N) {
  __shared__ int hist[NBINMAX];
  __shared__ int gbase[NBINMAX];
  __shared__ int lcur[NBINMAX];
  int t = threadIdx.x;
  int tot = E + N;
  int base = blockIdx.x * 4096;
  hist[t] = 0;
  __syncthreads();
  int sarr[16], darr[16];
  #pragma unroll
  for (int k = 0; k < 16; ++k) {
    int i = base + k * 256 + t;
    if (i < tot) {
      int s, d;
      if (i < E) { s = ei[i]; d = ei[E + i]; } else { s = i - E; d = s; }
      sarr[k] = s; darr[k] = d;
      atomicAdd(&hist[d >> 9], 1);
    } else darr[k] = -1;
  }
  __syncthreads();
  int c = hist[t];
  gbase[t] = (c > 0) ? atomicAdd(&gcur[t], c) : 0;
  lcur[t] = 0;
  __syncthreads();
  #pragma unroll
  for (int k = 0; k < 16; ++k) {
    int d = darr[k];
    if (d >= 0) {
      int b = d >> 9;
      int p = gbase[b] + atomicAdd(&lcur[b], 1);
      pairs[p] = ((unsigned int)(d & 511) << 17) | (unsigned int)sarr[k];
    }
  }
}

// ---------------- edge partition, level 2: exact CSR within bin ----------------

__global__ __launch_bounds__(256) void part_p2(const unsigned int* __restrict__ pairs,
                                               const int* __restrict__ gcur,
                                               int* __restrict__ ssrc,
                                               int* __restrict__ offsets,
                                               int* __restrict__ counts, int N) {
  __shared__ int ncnt[512], ncur[512], excl_s[512];
  __shared__ int wsum[4];
  int b = blockIdx.x;
  int t = threadIdx.x;
  int pb = b * STRIDE;
  int cnt = gcur[b] - pb;
  ncnt[t] = 0; ncnt[t + 256] = 0;
  __syncthreads();
  for (int e = t; e < cnt; e += 256) {
    unsigned int v = pairs[pb + e];
    atomicAdd(&ncnt[v >> 17], 1);
  }
  __syncthreads();
  int c0 = ncnt[2 * t], c1 = ncnt[2 * t + 1];
  int ps = c0 + c1;
  int lane = t & 63, w = t >> 6;
  int x = ps;
  #pragma unroll
  for (int s = 1; s < 64; s <<= 1) { int y = __shfl_up(x, s); if (lane >= s) x += y; }
  if (lane == 63) wsum[w] = x;
  __syncthreads();
  int woff = 0;
  for (int i = 0; i < w; ++i) woff += wsum[i];
  int ep = woff + x - ps;
  excl_s[2 * t]     = ep;
  excl_s[2 * t + 1] = ep + c0;
  __syncthreads();
  int binstart = b << 9;
  for (int i = t; i < 512; i += 256) {
    ncur[i] = excl_s[i];
    int node = binstart + i;
    if (node < N) { offsets[node] = pb + excl_s[i]; counts[node] = ncnt[i]; }
  }
  __syncthreads();
  for (int e = t; e < cnt; e += 256) {
    unsigned int v = pairs[pb + e];
    int dl = v >> 17;
    int p = atomicAdd(&ncur[dl], 1);
    ssrc[pb + p] = (int)(v & 0x1FFFF);
  }
}

// ---------------- graph boundaries (batch is sorted) ----------------

__global__ __launch_bounds__(256) void gbounds(const int* __restrict__ batch,
                                               int* __restrict__ gstart, int N) {
  int i = blockIdx.x * 256 + threadIdx.x;
  if (i >= N) return;
  int g = batch[i];
  if (i == 0 || batch[i - 1] != g) gstart[g] = i;
}

// wave-parallel: suffix-min of valid starts gives each graph's end
__global__ __launch_bounds__(64) void gfix(const int* __restrict__ gstart,
                                           int* __restrict__ go,
                                           int* __restrict__ ge, int N) {
  int g = threadIdx.x;                 // 64 lanes = 64 graphs
  int s = gstart[g];
  int v = (s < 0) ? 0x7FFFFFFF : s;
  int suf = v;
  #pragma unroll
  for (int off = 1; off < 64; off <<= 1) {
    int x = __shfl_down(suf, off);
    if (g + off < 64) suf = min(suf, x);
  }
  int nxt = __shfl_down(suf, 1);       // suffix-min over lanes > g
  if (g == 63) nxt = 0x7FFFFFFF;
  int e = nxt == 0x7FFFFFFF ? N : nxt;
  if (s < 0) { go[g] = e; ge[g] = e; }
  else       { go[g] = s; ge[g] = e; }
}

// ---------------- prep: weight transpose/split + gcur init ----------------

__global__ __launch_bounds__(256) void wprep(const float* __restrict__ w0,
                                             const float* __restrict__ w1,
                                             unsigned short* __restrict__ wt,
                                             int* __restrict__ gcur) {
  if (blockIdx.x == 0) gcur[threadIdx.x] = threadIdx.x * STRIDE;
  int idx = blockIdx.x * 256 + threadIdx.x;   // 0..32767
  int layer = idx >> 14;
  int e = idx & 16383;
  int k = e >> 7, n = e & 127;
  float v = (layer ? w1 : w0)[e];
  unsigned short hi = bf16rne(v);
  float hif = __uint_as_float((unsigned int)hi << 16);
  unsigned short lo = bf16rne(v - hif);
  unsigned short* basep = wt + layer * 32768;
  basep[n * 128 + k] = hi;
  basep[16384 + n * 128 + k] = lo;
}

// ---------------- MFMA bf16-split GEMM [N,128]@[128,128] + attn logits ----
// R13-proven structure: column-split grid (block = 128 rows x 64 cols);
// wave w: head w&1, row-half w>>1. LDS stages x once per block.
// BF16IN=0: fp32 input, truncation split into xh+xl, 6 MFMA/rt.
// BF16IN=1: packed-bf16 input (y from previous layer) -> xl==0: no convert,
//           no xl LDS, 4 MFMA/rt (xh x {wh,wl}).

template <int BF16IN>
__global__ __launch_bounds__(256) void gemm_mfma(
    const void* __restrict__ in_, const unsigned short* __restrict__ wtL,
    const float* __restrict__ att_s, const float* __restrict__ att_d,
    unsigned int* __restrict__ h16, float* __restrict__ a_s,
    float* __restrict__ a_d, int N) {
  __shared__ unsigned short xh[128][40];                 // [row][k] bf16 hi
  __shared__ unsigned short xl[BF16IN ? 1 : 128][40];    // lo plane (fp32 in only)
  int t = threadIdx.x;
  int bid = blockIdx.x;
  int ch = bid & 1;               // column half (heads 2ch, 2ch+1)
  int base = (bid >> 1) * 128;    // row base
  int lane = t & 63, w = t >> 6;
  int l15 = lane & 15, lg = lane >> 4;
  int hd = w & 1;                 // head within this col-half
  int n0 = ch * 64 + hd * 32;     // global col base for this wave
  int rh = w >> 1;                // row half (0: rows 0-63, 1: 64-127)

  f32x4 zero4 = {0.f, 0.f, 0.f, 0.f};
  f32x4 acc[4][2];
  #pragma unroll
  for (int rt = 0; rt < 4; ++rt) { acc[rt][0] = zero4; acc[rt][1] = zero4; }

  // x staging assignment: thread stages row sr, k-half sc
  int sr = t >> 1;
  int sc = (t & 1) * 16;
  int gr = base + sr;
  int rc = gr < N ? gr : (N - 1);
  const float* xpf = (const float*)in_ + (size_t)rc * 128 + sc;
  const unsigned int* xpb = (const unsigned int*)in_ + (size_t)rc * 64 + (sc >> 1);

  // B-frag row pointers (ushort elements; +16384 = lo plane)
  const unsigned short* wh0 = &wtL[(size_t)(n0 + l15) * 128];
  const unsigned short* wh1 = &wtL[(size_t)(n0 + 16 + l15) * 128];

  // prologue: preload kt=0 x tile and B frags
  float4 u0, u1, u2, u3;
  uint4 p0, p1;
  if constexpr (!BF16IN) {
    u0 = *(const float4*)(xpf + 0);
    u1 = *(const float4*)(xpf + 4);
    u2 = *(const float4*)(xpf + 8);
    u3 = *(const float4*)(xpf + 12);
  } else {
    p0 = *(const uint4*)(xpb + 0);
    p1 = *(const uint4*)(xpb + 4);
  }
  short8 cbh0 = *(const short8*)(wh0 + lg * 8);
  short8 cbh1 = *(const short8*)(wh1 + lg * 8);
  short8 cbl0 = *(const short8*)(wh0 + 16384 + lg * 8);
  short8 cbl1 = *(const short8*)(wh1 + 16384 + lg * 8);

  #pragma unroll
  for (int kt = 0; kt < 4; ++kt) {
    if (kt) __syncthreads();   // prev iteration's LDS reads complete
    // stage this tile's x into LDS
    if constexpr (!BF16IN) {
      float4 uu[4] = {u0, u1, u2, u3};
      #pragma unroll
      for (int q = 0; q < 4; ++q) {
        float4 u = uu[q];
        unsigned int b0 = __float_as_uint(u.x), b1 = __float_as_uint(u.y);
        unsigned int b2 = __float_as_uint(u.z), b3 = __float_as_uint(u.w);
        *(unsigned int*)&xh[sr][sc + q * 4]     = __builtin_amdgcn_perm(b1, b0, 0x07060302u);
        *(unsigned int*)&xh[sr][sc + q * 4 + 2] = __builtin_amdgcn_perm(b3, b2, 0x07060302u);
        float r0 = u.x - __uint_as_float(b0 & 0xFFFF0000u);
        float r1 = u.y - __uint_as_float(b1 & 0xFFFF0000u);
        float r2 = u.z - __uint_as_float(b2 & 0xFFFF0000u);
        float r3 = u.w - __uint_as_float(b3 & 0xFFFF0000u);
        *(unsigned int*)&xl[sr][sc + q * 4] =
            __builtin_amdgcn_perm(__float_as_uint(r1), __float_as_uint(r0), 0x07060302u);
        *(unsigned int*)&xl[sr][sc + q * 4 + 2] =
            __builtin_amdgcn_perm(__float_as_uint(r3), __float_as_uint(r2), 0x07060302u);
      }
    } else {
      *(uint4*)&xh[sr][sc]     = p0;
      *(uint4*)&xh[sr][sc + 8] = p1;
    }
    __syncthreads();           // LDS tile ready
    // prefetch next tile (x regs + B frags) — hidden under MFMA below
    float4 v0, v1, v2, v3;
    uint4 q0, q1;
    if constexpr (!BF16IN) { v0 = u0; v1 = u1; v2 = u2; v3 = u3; }
    else { q0 = p0; q1 = p1; }
    short8 nbh0 = cbh0, nbh1 = cbh1, nbl0 = cbl0, nbl1 = cbl1;
    if (kt < 3) {
      int k1 = (kt + 1) * 32;
      if constexpr (!BF16IN) {
        v0 = *(const float4*)(xpf + k1);
        v1 = *(const float4*)(xpf + k1 + 4);
        v2 = *(const float4*)(xpf + k1 + 8);
        v3 = *(const float4*)(xpf + k1 + 12);
      } else {
        q0 = *(const uint4*)(xpb + (k1 >> 1));
        q1 = *(const uint4*)(xpb + (k1 >> 1) + 4);
      }
      nbh0 = *(const short8*)(wh0 + k1 + lg * 8);
      nbh1 = *(const short8*)(wh1 + k1 + lg * 8);
      nbl0 = *(const short8*)(wh0 + 16384 + k1 + lg * 8);
      nbl1 = *(const short8*)(wh1 + 16384 + k1 + lg * 8);
    }
    // A-frags + MFMA (rows rh*64 + rt*16 + l15)
    #pragma unroll
    for (int rt = 0; rt < 4; ++rt) {
      int row = rh * 64 + rt * 16 + l15;
      short8 fah = *(const short8*)&xh[row][lg * 8];
      acc[rt][0] = __builtin_amdgcn_mfma_f32_16x16x32_bf16(fah, cbh0, acc[rt][0], 0, 0, 0);
      acc[rt][1] = __builtin_amdgcn_mfma_f32_16x16x32_bf16(fah, cbh1, acc[rt][1], 0, 0, 0);
      if constexpr (!BF16IN) {
        short8 fal = *(const short8*)&xl[row][lg * 8];
        acc[rt][0] = __builtin_amdgcn_mfma_f32_16x16x32_bf16(fal, cbh0, acc[rt][0], 0, 0, 0);
        acc[rt][1] = __builtin_amdgcn_mfma_f32_16x16x32_bf16(fal, cbh1, acc[rt][1], 0, 0, 0);
      }
      acc[rt][0] = __builtin_amdgcn_mfma_f32_16x16x32_bf16(fah, cbl0, acc[rt][0], 0, 0, 0);
      acc[rt][1] = __builtin_amdgcn_mfma_f32_16x16x32_bf16(fah, cbl1, acc[rt][1], 0, 0, 0);
    }
    if constexpr (!BF16IN) { u0 = v0; u1 = v1; u2 = v2; u3 = v3; }
    else { p0 = q0; p1 = q1; }
    cbh0 = nbh0; cbh1 = nbh1; cbl0 = nbl0; cbl1 = nbl1;
  }

  // ---- epilogue: h16 (pack adjacent cols via shfl) + exact attn logits ----
  int headg = ch * 2 + hd;
  float as0 = att_s[n0 + l15], as1 = att_s[n0 + 16 + l15];
  float ad0 = att_d[n0 + l15], ad1 = att_d[n0 + 16 + l15];
  #pragma unroll
  for (int rt = 0; rt < 4; ++rt) {
    float ps[4], pd[4];
    #pragma unroll
    for (int q = 0; q < 4; ++q) {
      float c0v = acc[rt][0][q], c1v = acc[rt][1][q];
      float pp0 = __shfl_xor(c0v, 1), pp1 = __shfl_xor(c1v, 1);
      int row = base + rh * 64 + rt * 16 + lg * 4 + q;
      if (!(l15 & 1) && row < N) {
        h16[(size_t)row * 64 + (n0 + l15) / 2]      = pack2(c0v, pp0);
        h16[(size_t)row * 64 + (n0 + 16 + l15) / 2] = pack2(c1v, pp1);
      }
      ps[q] = c0v * as0 + c1v * as1;
      pd[q] = c0v * ad0 + c1v * ad1;
    }
    #pragma unroll
    for (int m = 1; m <= 8; m <<= 1) {
      #pragma unroll
      for (int q = 0; q < 4; ++q) { ps[q] += __shfl_xor(ps[q], m); pd[q] += __shfl_xor(pd[q], m); }
    }
    if (l15 == 0) {
      #pragma unroll
      for (int q = 0; q < 4; ++q) {
        int row = base + rh * 64 + rt * 16 + lg * 4 + q;
        if (row < N) { a_s[row * 4 + headg] = ps[q]; a_d[row * 4 + headg] = pd[q]; }
      }
    }
  }
}

// ---------------- GAT aggregation, wave per dst node (R9 structure) ----------------
// Output y is packed bf16 (one uint per lane) — feeds gemm<BF16IN=1> / pool.

#define ACCP(EX, V0, V1)                                                       \
  { float2 ex2 = make_float2(EX, EX);                                          \
    acc2[0] += ex2 * make_float2(blo(V0.x), bhi(V0.x));                        \
    acc2[1] += ex2 * make_float2(blo(V0.y), bhi(V0.y));                        \
    acc2[2] += ex2 * make_float2(blo(V0.z), bhi(V0.z));                        \
    acc2[3] += ex2 * make_float2(blo(V0.w), bhi(V0.w));                        \
    acc2[4] += ex2 * make_float2(blo(V1.x), bhi(V1.x));                        \
    acc2[5] += ex2 * make_float2(blo(V1.y), bhi(V1.y));                        \
    acc2[6] += ex2 * make_float2(blo(V1.z), bhi(V1.z));                        \
    acc2[7] += ex2 * make_float2(blo(V1.w), bhi(V1.w)); }

__global__ __launch_bounds__(256) void gat_aggregate(
    const unsigned int* __restrict__ h16, const float* __restrict__ a_s, const float* __restrict__ a_d,
    const int* __restrict__ offsets, const int* __restrict__ counts, const int* __restrict__ ssrc,
    const float* __restrict__ bias,
    const float* __restrict__ bn_g, const float* __restrict__ bn_b,
    const float* __restrict__ bn_m, const float* __restrict__ bn_v,
    unsigned int* __restrict__ y16, int N) {
  __shared__ float part[4][8][132];
  int wv = threadIdx.x >> 6;
  int lane = threadIdx.x & 63;
  int wid = blockIdx.x * 4 + wv;
  if (wid >= N) return;
  int off = offsets[wid], cnt = counts[wid];
  int eg = lane >> 3;          // edge group 0..7
  int j  = lane & 7;           // owns dims j*16 .. j*16+15
  int hh = j >> 1;             // head of those dims
  float ad = a_d[wid * 4 + hh];

  float2 acc2[8] = {};
  float den = 0.f;

  int sA = ssrc[off + (eg < cnt ? eg : 0)];
  int iB0 = eg + 8;
  int sB = ssrc[off + (iB0 < cnt ? iB0 : 0)];
  float asA = a_s[sA * 4 + hh];
  float asB = a_s[sB * 4 + hh];

  for (int i = eg; i < cnt; i += 16) {
    const uint4* hpA = (const uint4*)(h16 + (size_t)sA * 64 + j * 8);
    uint4 va0 = hpA[0], va1 = hpA[1];
    const uint4* hpB = (const uint4*)(h16 + (size_t)sB * 64 + j * 8);
    uint4 vb0 = hpB[0], vb1 = hpB[1];
    int in0 = i + 16, in1 = i + 24;
    int snA = ssrc[off + (in0 < cnt ? in0 : 0)];
    int snB = ssrc[off + (in1 < cnt ? in1 : 0)];
    float anA = a_s[snA * 4 + hh];
    float anB = a_s[snB * 4 + hh];
    float eA = asA + ad; eA = eA > 0.f ? eA : 0.2f * eA;
    float exA = __expf(eA);
    float eB = asB + ad; eB = eB > 0.f ? eB : 0.2f * eB;
    float exB = ((i + 8) < cnt) ? __expf(eB) : 0.f;
    den += exA + exB;
    ACCP(exA, va0, va1)
    ACCP(exB, vb0, vb1)
    sA = snA; sB = snB; asA = anA; asB = anB;
  }

  den += __shfl_xor(den, 8);
  den += __shfl_xor(den, 16);
  den += __shfl_xor(den, 32);
  den = __shfl(den, (lane >> 4) * 2);

  float* pw = &part[wv][eg][j * 16];
  *(float4*)(pw + 0)  = make_float4(acc2[0].x, acc2[0].y, acc2[1].x, acc2[1].y);
  *(float4*)(pw + 4)  = make_float4(acc2[2].x, acc2[2].y, acc2[3].x, acc2[3].y);
  *(float4*)(pw + 8)  = make_float4(acc2[4].x, acc2[4].y, acc2[5].x, acc2[5].y);
  *(float4*)(pw + 12) = make_float4(acc2[6].x, acc2[6].y, acc2[7].x, acc2[7].y);
  asm volatile("s_waitcnt lgkmcnt(0)" ::: "memory");

  int d = lane * 2;
  float r0 = 0.f, r1 = 0.f;
  #pragma unroll
  for (int g = 0; g < 8; ++g) {
    float2 v = *(const float2*)(&part[wv][g][d]);
    r0 += v.x; r1 += v.y;
  }

  float inv = 1.f / (den + 1e-16f);
  float2 bi = *(const float2*)(&bias[d]);
  float2 g2 = *(const float2*)(&bn_g[d]);
  float2 b2 = *(const float2*)(&bn_b[d]);
  float2 m2 = *(const float2*)(&bn_m[d]);
  float2 v2 = *(const float2*)(&bn_v[d]);
  float o0 = r0 * inv + bi.x;
  float o1 = r1 * inv + bi.y;
  o0 = fmaxf((o0 - m2.x) * (g2.x * rsqrtf(v2.x + 1e-5f)) + b2.x, 0.f);
  o1 = fmaxf((o1 - m2.y) * (g2.y * rsqrtf(v2.y + 1e-5f)) + b2.y, 0.f);
  y16[(size_t)wid * 64 + lane] = pack2(o0, o1);
}

// ---------------- global mean pool (partial) + head MLP ----------------

#define POOLP 8

__global__ __launch_bounds__(256) void pool_kernel(const unsigned int* __restrict__ y16,
                                                   const int* __restrict__ go,
                                                   const int* __restrict__ ge,
                                                   float* __restrict__ pooled) {
  int g = blockIdx.x / POOLP, p = blockIdx.x % POOLP;
  int s = go[g], e = ge[g];
  int len = e - s;
  int q0 = s + (len * p) / POOLP, q1 = s + (len * (p + 1)) / POOLP;
  int t = threadIdx.x;
  int d = t & 127, half = t >> 7;
  int du = d >> 1, dodd = d & 1;
  float acc = 0.f;
  for (int i = q0 + half; i < q1; i += 2) {
    unsigned int v = y16[(size_t)i * 64 + du];
    acc += dodd ? bhi(v) : blo(v);
  }
  __shared__ float red[256];
  red[t] = acc;
  __syncthreads();
  if (half == 0) atomicAdd(&pooled[g * 128 + d], red[d] + red[d + 128]);
}

__global__ __launch_bounds__(64) void mlp_kernel(const float* __restrict__ pooled,
                                                 const int* __restrict__ go,
                                                 const int* __restrict__ ge,
                                                 const float* __restrict__ w1,
                                                 const float* __restrict__ b1,
                                                 const float* __restrict__ w2,
                                                 const float* __restrict__ b2,
                                                 float* __restrict__ out) {
  int g = blockIdx.x, j = threadIdx.x;
  int cnt = ge[g] - go[g];
  float inv = 1.f / (float)(cnt > 1 ? cnt : 1);
  float z = b1[j];
  for (int k = 0; k < 128; ++k) z += pooled[g * 128 + k] * inv * w1[k * 64 + j];
  z = fmaxf(z, 0.f);
  float v = z * w2[j];
  #pragma unroll
  for (int m = 1; m < 64; m <<= 1) v += __shfl_xor(v, m);
  if (j == 0) out[g] = v + b2[0];
}

// ---------------- launch ----------------

extern "C" void kernel_launch(void* const* d_in, const int* in_sizes, int n_in,
                              void* d_out, int out_size, void* d_ws, size_t ws_size,
                              hipStream_t stream) {
  const float* x     = (const float*)d_in[0];
  const int*   ei    = (const int*)d_in[1];
  const int*   batch = (const int*)d_in[2];
  const float* w0    = (const float*)d_in[3];
  const float* atts0 = (const float*)d_in[4];
  const float* attd0 = (const float*)d_in[5];
  const float* bias0 = (const float*)d_in[6];
  const float* w1    = (const float*)d_in[7];
  const float* atts1 = (const float*)d_in[8];
  const float* attd1 = (const float*)d_in[9];
  const float* bias1 = (const float*)d_in[10];
  const float* bng0  = (const float*)d_in[11];
  const float* bnb0  = (const float*)d_in[12];
  const float* bnm0  = (const float*)d_in[13];
  const float* bnv0  = (const float*)d_in[14];
  const float* bng1  = (const float*)d_in[15];
  const float* bnb1  = (const float*)d_in[16];
  const float* bnm1  = (const float*)d_in[17];
  const float* bnv1  = (const float*)d_in[18];
  const float* l1w   = (const float*)d_in[19];
  const float* l1b   = (const float*)d_in[20];
  const float* l2w   = (const float*)d_in[21];
  const float* l2b   = (const float*)d_in[22];

  int N = in_sizes[2];        // batch length
  int E = in_sizes[1] / 2;    // edge_index is [2,E]
  int tot = E + N;
  int NBIN = (N + 511) / 512;

  char* p = (char*)d_ws;
  unsigned int* h16 = (unsigned int*)p; p += (size_t)N * 64 * 4;  // bf16 h payload
  unsigned int* y16 = (unsigned int*)p; p += (size_t)N * 64 * 4;  // bf16 y (inter-layer)
  float* a_s    = (float*)p; p += (size_t)N * 4 * 4;
  float* a_d    = (float*)p; p += (size_t)N * 4 * 4;
  int* counts   = (int*)p;   p += (size_t)N * 4;
  int* offsets  = (int*)p;   p += (size_t)N * 4;
  int* ssrc     = (int*)p;   p += (size_t)NBINMAX * STRIDE * 4;
  int* gcur     = (int*)p;   p += NBINMAX * 4;
  int* gstart   = (int*)p;   p += 64 * 4;
  int* go       = (int*)p;   p += 64 * 4;
  int* ge       = (int*)p;   p += 64 * 4;
  float* pooled = (float*)p; p += 64 * 128 * 4;
  unsigned short* wt = (unsigned short*)p; p += 2 * 32768 * 2;  // [2][hi/lo][n][k]
  // pairs buffer aliases y16 (25.6 MB >= 10.5 MB needed; dead before y16 written)
  unsigned int* pairs = y16;

  hipMemsetAsync(gstart, 0xFF, 64 * 4, stream);
  hipMemsetAsync(pooled, 0, 64 * 128 * 4, stream);

  int bN = (N + 255) / 256;
  int bW = (N + 3) / 4;              // wave-per-node kernels
  int bG2 = 2 * ((N + 127) / 128);   // gemm: row tiles x 2 col-halves

  wprep<<<128, 256, 0, stream>>>(w0, w1, wt, gcur);   // also inits gcur
  part_p1<<<(tot + 4095) / 4096, 256, 0, stream>>>(ei, gcur, pairs, E, N);
  part_p2<<<NBIN, 256, 0, stream>>>(pairs, gcur, ssrc, offsets, counts, N);
  gbounds<<<bN, 256, 0, stream>>>(batch, gstart, N);
  gfix<<<1, 64, 0, stream>>>(gstart, go, ge, N);

  // layer 0 (fp32 input)
  gemm_mfma<0><<<bG2, 256, 0, stream>>>(x, wt, atts0, attd0, h16, a_s, a_d, N);
  gat_aggregate<<<bW, 256, 0, stream>>>(h16, a_s, a_d, offsets, counts, ssrc,
                                        bias0, bng0, bnb0, bnm0, bnv0, y16, N);
  // layer 1 (bf16 input)
  gemm_mfma<1><<<bG2, 256, 0, stream>>>(y16, wt + 32768, atts1, attd1, h16, a_s, a_d, N);
  gat_aggregate<<<bW, 256, 0, stream>>>(h16, a_s, a_d, offsets, counts, ssrc,
                                        bias1, bng1, bnb1, bnm1, bnv1, y16, N);
  // pool + head
  pool_kernel<<<GG * POOLP, 256, 0, stream>>>(y16, go, ge, pooled);
  mlp_kernel<<<GG, 64, 0, stream>>>(pooled, go, ge, l1w, l1b, l2w, l2b, (float*)d_out);
}